// Round 1
// 1627.576 us; speedup vs baseline: 1.6287x; 1.6287x over previous
//
#include <hip/hip_runtime.h>

typedef unsigned short ushort_t;
typedef unsigned int uint_t;
typedef __attribute__((ext_vector_type(4))) float f32x4;
typedef __attribute__((ext_vector_type(8))) __bf16 bf16x8;

constexpr int BB = 32, SS = 128, EE = 512, HH = 512, VV = 32000;
constexpr int MM = BB * SS;   // 4096
constexpr int G3 = 3 * HH;    // 1536
constexpr int SCAN_WG = 32;   // 32 WGs, each owns 16 hidden cols (48 W_hh rows in LDS)

__device__ inline ushort_t f2b(float f) {
  union { float f; uint_t u; } v; v.f = f;
  uint_t r = v.u + 0x7fffu + ((v.u >> 16) & 1u);
  return (ushort_t)(r >> 16);
}
__device__ inline float b2f(ushort_t u) {
  union { float f; uint_t u; } v; v.u = ((uint_t)u) << 16;
  return v.f;
}

// ---------------- f32 -> bf16 converters ----------------
__global__ void cvt_bf16(const float* __restrict__ s, ushort_t* __restrict__ d, int n4) {
  int i = blockIdx.x * blockDim.x + threadIdx.x;
  if (i >= n4) return;
  float4 v = reinterpret_cast<const float4*>(s)[i];
  ushort4 o;
  o.x = f2b(v.x); o.y = f2b(v.y); o.z = f2b(v.z); o.w = f2b(v.w);
  reinterpret_cast<ushort4*>(d)[i] = o;
}

__global__ void cvt_split(const float* __restrict__ s, ushort_t* __restrict__ hi,
                          ushort_t* __restrict__ lo, int n4) {
  int i = blockIdx.x * blockDim.x + threadIdx.x;
  if (i >= n4) return;
  float4 v = reinterpret_cast<const float4*>(s)[i];
  float a[4] = {v.x, v.y, v.z, v.w};
  ushort4 oh, ol;
  ushort_t h;
  h = f2b(a[0]); oh.x = h; ol.x = f2b(a[0] - b2f(h));
  h = f2b(a[1]); oh.y = h; ol.y = f2b(a[1] - b2f(h));
  h = f2b(a[2]); oh.z = h; ol.z = f2b(a[2] - b2f(h));
  h = f2b(a[3]); oh.w = h; ol.w = f2b(a[3] - b2f(h));
  reinterpret_cast<ushort4*>(hi)[i] = oh;
  reinterpret_cast<ushort4*>(lo)[i] = ol;
}

// ---------------- bf16 B^T GEMM: C[M,N] = A[M,K] * B[N,K]^T (+bias[n]) ----------------
// 128x128 tile, 256 threads (4 waves, 2x2 wave grid of 64x64), BK=32,
// global_load_lds width-16 staging (m97 structure). Unchanged.
__global__ __launch_bounds__(256) void gemm_bt(
    const ushort_t* __restrict__ A, const ushort_t* __restrict__ B,
    float* __restrict__ C, const float* __restrict__ bias,
    int M, int N, int K) {
  __shared__ alignas(16) ushort_t As[128 * 32];
  __shared__ alignas(16) ushort_t Bs[128 * 32];
  const int tid = threadIdx.x;
  const int wave = tid >> 6, lane = tid & 63;
  const int l16 = lane & 15, quad = lane >> 4;
  const int m0 = blockIdx.x * 128, n0 = blockIdx.y * 128;
  const int wm = (wave & 1) * 64, wn = (wave >> 1) * 64;

  f32x4 acc[4][4] = {};
  const int cbase = wave * 64 + lane;  // chunk id, pass 0

  for (int kt = 0; kt < K; kt += 32) {
#pragma unroll
    for (int pass = 0; pass < 2; ++pass) {
      int c = cbase + pass * 256;     // 16B chunk index in tile [0,512)
      int r = c >> 2;                 // tile row
      int kc = (c & 3) * 8;           // bf16 elems into the 32-wide k slab
      const ushort_t* ga = A + (size_t)(m0 + r) * K + kt + kc;
      const ushort_t* gb = B + (size_t)(n0 + r) * K + kt + kc;
      int ldsoff = (wave * 64 + pass * 256) * 16;  // bytes, wave-uniform
      __builtin_amdgcn_global_load_lds(
          (const __attribute__((address_space(1))) void*)ga,
          (__attribute__((address_space(3))) void*)((char*)As + ldsoff), 16, 0, 0);
      __builtin_amdgcn_global_load_lds(
          (const __attribute__((address_space(1))) void*)gb,
          (__attribute__((address_space(3))) void*)((char*)Bs + ldsoff), 16, 0, 0);
    }
    __syncthreads();
    bf16x8 af[4], bf[4];
#pragma unroll
    for (int i = 0; i < 4; ++i)
      af[i] = *(const bf16x8*)&As[(wm + i * 16 + l16) * 32 + quad * 8];
#pragma unroll
    for (int j = 0; j < 4; ++j)
      bf[j] = *(const bf16x8*)&Bs[(wn + j * 16 + l16) * 32 + quad * 8];
#pragma unroll
    for (int i = 0; i < 4; ++i)
#pragma unroll
      for (int j = 0; j < 4; ++j)
        acc[i][j] = __builtin_amdgcn_mfma_f32_16x16x32_bf16(af[i], bf[j], acc[i][j], 0, 0, 0);
    __syncthreads();
  }
  // epilogue: D row = quad*4+reg, col = lane&15 (m89-verified layout)
#pragma unroll
  for (int i = 0; i < 4; ++i) {
    int row = m0 + wm + i * 16 + quad * 4;
#pragma unroll
    for (int j = 0; j < 4; ++j) {
      int col = n0 + wn + j * 16 + l16;
      float bv = bias ? bias[col] : 0.0f;
#pragma unroll
      for (int r = 0; r < 4; ++r)
        C[(size_t)(row + r) * N + col] = acc[i][j][r] + bv;
    }
  }
}

// ---------------- persistent GRU scan, v2 ----------------
// 32 WGs; WG g owns hidden cols [g*16, g*16+16) -> 48 W_hh rows (3 gates x 16).
// W_hh hi/lo slice lives in LDS for the WHOLE scan (96 KB, XOR-swizzled) so the
// per-step device-fence L2 invalidation no longer forces L3-latency W_hh reloads
// (that reload chain was ~13 of the 14.6 us/step).
// Per step: waves K-split the [32 x 48] GEMM (each wave K=128, 6 independent acc
// chains, 72 MFMA) -> LDS partial reduce -> gates -> h ring -> grid barrier.
__global__ __launch_bounds__(256) void gru_scan(
    const float* __restrict__ xg,        // [4096,1536], row m=b*S+s
    const float* __restrict__ h0,        // [32,512]
    const float* __restrict__ b_hh,      // [1536]
    const ushort_t* __restrict__ whh_hi, // [1536,512]
    const ushort_t* __restrict__ whh_lo,
    float* __restrict__ hf32,            // ring [2][32*512]
    ushort_t* __restrict__ hbhi,         // ring [2][32*512]
    ushort_t* __restrict__ hblo,
    ushort_t* __restrict__ hs,           // [4096,512] bf16, row m=b*S+t
    int* __restrict__ bar) {
  const int g = blockIdx.x;
  const int tid = threadIdx.x;
  const int wave = tid >> 6, lane = tid & 63;
  const int l16 = lane & 15, quad = lane >> 4;

  // 48 KB + 48 KB + 25.5 KB = 121.5 KB LDS -> 1 WG/CU, 32 CUs used.
  __shared__ alignas(16) ushort_t lds_whh_hi[48 * 512];
  __shared__ alignas(16) ushort_t lds_whh_lo[48 * 512];
  __shared__ float lds_part[4][3][32][17];

  // ---- one-time: stage this WG's W_hh slice into LDS, XOR-swizzled ----
  // layout: local row lr = sec*16 + i  (global row sec*512 + g*16 + i),
  // byte addr = lr*1024 + (kbyte ^ ((lr&7)<<4)).  16B granularity preserved;
  // B-frag ds_read_b128 then hits 8 distinct 16B slots across lanes 0..7
  // (2-way aliasing for lanes 8..15 = free, m136).
  for (int c = tid; c < 48 * 64; c += 256) {
    int lr = c >> 6;                 // 0..47
    int kc = c & 63;                 // 16B chunk within row
    int grow = (lr >> 4) * 512 + g * 16 + (lr & 15);
    const f32x4* srch = (const f32x4*)(whh_hi + (size_t)grow * 512 + kc * 8);
    const f32x4* srcl = (const f32x4*)(whh_lo + (size_t)grow * 512 + kc * 8);
    int db = lr * 1024 + ((kc * 16) ^ ((lr & 7) << 4));
    *(f32x4*)((char*)lds_whh_hi + db) = *srch;
    *(f32x4*)((char*)lds_whh_lo + db) = *srcl;
  }
  __syncthreads();

  // ---- gate-phase per-thread geometry: 2 (b, col) outputs ----
  const int gb = tid >> 3;          // batch 0..31
  const int jj = (tid & 7) * 2;     // local col 0,2,..,14
  const int gj = g * 16 + jj;       // global hidden col
  const float bh_r0 = b_hh[gj],        bh_r1 = b_hh[gj + 1];
  const float bh_z0 = b_hh[512 + gj],  bh_z1 = b_hh[512 + gj + 1];
  const float bh_n0 = b_hh[1024 + gj], bh_n1 = b_hh[1024 + gj + 1];
  const float* xgp0 = xg + (size_t)gb * SS * G3 + gj;

  for (int t = 0; t < SS; ++t) {
    const int p = t & 1;

    // ---- issue gate-phase global loads FIRST (independent of h): hidden
    // under the GEMM phase below.
    const float* xgp = xgp0 + (size_t)t * G3;
    float2 fxr = *(const float2*)(xgp);
    float2 fxz = *(const float2*)(xgp + 512);
    float2 fxn = *(const float2*)(xgp + 1024);
    float2 fhv = (t == 0) ? *(const float2*)(h0 + gb * HH + gj)
                          : *(const float2*)(hf32 + p * (BB * HH) + gb * HH + gj);

    // ---- GEMM phase: hg[32,48] = h[32,512] @ Whh_slice^T, split-bf16.
    // Wave w covers K in [w*128, w*128+128): 6 independent acc chains.
    {
      const ushort_t* hhi = hbhi + p * (BB * HH);
      const ushort_t* hlo = hblo + p * (BB * HH);
      f32x4 acc[2][3] = {};
      const int kbase = wave * 128;
#pragma unroll
      for (int kk = 0; kk < 4; ++kk) {
        const int kw = kbase + kk * 32 + quad * 8;
        bf16x8 ah[2], al[2];
#pragma unroll
        for (int mt = 0; mt < 2; ++mt) {
          ah[mt] = *(const bf16x8*)(hhi + (size_t)(mt * 16 + l16) * HH + kw);
          al[mt] = *(const bf16x8*)(hlo + (size_t)(mt * 16 + l16) * HH + kw);
        }
        bf16x8 bh[3], bl[3];
#pragma unroll
        for (int nt = 0; nt < 3; ++nt) {
          int lr = nt * 16 + l16;
          int db = lr * 1024 + ((kw * 2) ^ ((lr & 7) << 4));
          bh[nt] = *(const bf16x8*)((const char*)lds_whh_hi + db);
          bl[nt] = *(const bf16x8*)((const char*)lds_whh_lo + db);
        }
#pragma unroll
        for (int mt = 0; mt < 2; ++mt)
#pragma unroll
          for (int nt = 0; nt < 3; ++nt) {
            acc[mt][nt] = __builtin_amdgcn_mfma_f32_16x16x32_bf16(ah[mt], bh[nt], acc[mt][nt], 0, 0, 0);
            acc[mt][nt] = __builtin_amdgcn_mfma_f32_16x16x32_bf16(ah[mt], bl[nt], acc[mt][nt], 0, 0, 0);
            acc[mt][nt] = __builtin_amdgcn_mfma_f32_16x16x32_bf16(al[mt], bh[nt], acc[mt][nt], 0, 0, 0);
          }
      }
      // partials -> LDS (C layout: row = quad*4+r, col = l16)
#pragma unroll
      for (int mt = 0; mt < 2; ++mt)
#pragma unroll
        for (int nt = 0; nt < 3; ++nt)
#pragma unroll
          for (int r = 0; r < 4; ++r)
            lds_part[wave][nt][mt * 16 + quad * 4 + r][l16] = acc[mt][nt][r];
    }
    __syncthreads();

    // ---- gate phase: reduce 4 K-partials, apply GRU nonlinearity ----
    {
      float xra[2] = {fxr.x, fxr.y};
      float xza[2] = {fxz.x, fxz.y};
      float xna[2] = {fxn.x, fxn.y};
      float hva[2] = {fhv.x, fhv.y};
      float bra[2] = {bh_r0, bh_r1};
      float bza[2] = {bh_z0, bh_z1};
      float bna[2] = {bh_n0, bh_n1};
      float outv[2]; ushort_t ohi[2], olo[2];
#pragma unroll
      for (int c = 0; c < 2; ++c) {
        int col = jj + c;
        float hr = lds_part[0][0][gb][col] + lds_part[1][0][gb][col]
                 + lds_part[2][0][gb][col] + lds_part[3][0][gb][col] + bra[c];
        float hz = lds_part[0][1][gb][col] + lds_part[1][1][gb][col]
                 + lds_part[2][1][gb][col] + lds_part[3][1][gb][col] + bza[c];
        float hn = lds_part[0][2][gb][col] + lds_part[1][2][gb][col]
                 + lds_part[2][2][gb][col] + lds_part[3][2][gb][col] + bna[c];
        float r = 1.f / (1.f + __expf(-(xra[c] + hr)));
        float z = 1.f / (1.f + __expf(-(xza[c] + hz)));
        float pre = xna[c] + r * hn;
        pre = fminf(fmaxf(pre, -15.f), 15.f);
        float e = __expf(2.f * pre);
        float n = (e - 1.f) / (e + 1.f);
        float hnew = (1.f - z) * n + z * hva[c];
        outv[c] = hnew;
        ushort_t hb = f2b(hnew);
        ohi[c] = hb;
        olo[c] = f2b(hnew - b2f(hb));
      }
      float* hf_next = hf32 + (p ^ 1) * (BB * HH);
      ushort_t* hhi_n = hbhi + (p ^ 1) * (BB * HH);
      ushort_t* hlo_n = hblo + (p ^ 1) * (BB * HH);
      *(float2*)(hf_next + gb * HH + gj) = make_float2(outv[0], outv[1]);
      ushort2 uh; uh.x = ohi[0]; uh.y = ohi[1];
      ushort2 ul; ul.x = olo[0]; ul.y = olo[1];
      *(ushort2*)(hhi_n + gb * HH + gj) = uh;
      *(ushort2*)(hlo_n + gb * HH + gj) = ul;
      *(ushort2*)(hs + (size_t)(gb * SS + t) * HH + gj) = uh;
    }

    // ---- grid barrier (device-scope; 32 co-resident WGs) ----
    __syncthreads();                 // drains vmcnt before fence/arrive
    if (tid == 0) {
      __threadfence();               // release: L2 writeback, agent scope
      atomicAdd(bar, 1);
      int target = (t + 1) * SCAN_WG;
      // relaxed coherent LOAD poll (no RMW serialization across 32 pollers)
      while (__hip_atomic_load(bar, __ATOMIC_RELAXED, __HIP_MEMORY_SCOPE_AGENT) < target)
        __builtin_amdgcn_s_sleep(2);
      __threadfence();               // acquire: invalidate L1/L2
    }
    __syncthreads();
  }
}

extern "C" void kernel_launch(void* const* d_in, const int* in_sizes, int n_in,
                              void* d_out, int out_size, void* d_ws, size_t ws_size,
                              hipStream_t stream) {
  (void)in_sizes; (void)n_in; (void)out_size; (void)ws_size;
  const float* embed  = (const float*)d_in[0];  // [B,S,E]
  const float* hidden = (const float*)d_in[1];  // [1,B,H]
  const float* w_ih   = (const float*)d_in[2];  // [3H,E]
  const float* w_hh   = (const float*)d_in[3];  // [3H,H]
  const float* b_ih   = (const float*)d_in[4];  // [3H]
  const float* b_hh   = (const float*)d_in[5];  // [3H]
  const float* w_out  = (const float*)d_in[6];  // [V,H]
  float* out = (float*)d_out;

  char* ws = (char*)d_ws;
  size_t off = 0;
  auto alloc = [&](size_t bytes) {
    void* p = ws + off;
    off += (bytes + 255) & ~(size_t)255;
    return p;
  };
  float*    xg     = (float*)   alloc((size_t)MM * G3 * 4);   // 25.2 MB
  ushort_t* emb16  = (ushort_t*)alloc((size_t)MM * EE * 2);   // 4.2 MB
  ushort_t* wih16  = (ushort_t*)alloc((size_t)G3 * EE * 2);   // 1.5 MB
  ushort_t* whh_hi = (ushort_t*)alloc((size_t)G3 * HH * 2);   // 1.5 MB
  ushort_t* whh_lo = (ushort_t*)alloc((size_t)G3 * HH * 2);   // 1.5 MB
  ushort_t* wout16 = (ushort_t*)alloc((size_t)VV * HH * 2);   // 32.8 MB
  ushort_t* hs16   = (ushort_t*)alloc((size_t)MM * HH * 2);   // 4.2 MB
  float*    hf     = (float*)   alloc((size_t)2 * BB * HH * 4);
  ushort_t* hbhi   = (ushort_t*)alloc((size_t)2 * BB * HH * 2);
  ushort_t* hblo   = (ushort_t*)alloc((size_t)2 * BB * HH * 2);
  int*      bar    = (int*)     alloc(256);

  hipMemsetAsync(bar, 0, 256, stream);

  cvt_bf16 <<<2048,  256, 0, stream>>>(embed, emb16, MM * EE / 4);
  cvt_bf16 <<<768,   256, 0, stream>>>(w_ih, wih16, G3 * EE / 4);
  cvt_split<<<768,   256, 0, stream>>>(w_hh, whh_hi, whh_lo, G3 * HH / 4);
  cvt_bf16 <<<16000, 256, 0, stream>>>(w_out, wout16, VV * HH / 4);
  cvt_split<<<16,    256, 0, stream>>>(hidden, hbhi, hblo, BB * HH / 4);

  // x-gates: xg[m, g] = embed[m,:] . w_ih[g,:] + b_ih[g]
  gemm_bt<<<dim3(MM / 128, G3 / 128), 256, 0, stream>>>(emb16, wih16, xg, b_ih, MM, G3, EE);

  gru_scan<<<SCAN_WG, 256, 0, stream>>>(xg, hidden, b_hh, whh_hi, whh_lo,
                                        hf, hbhi, hblo, hs16, bar);

  // projection: out[m, v] = hs[m,:] . w_out[v,:]  (m = b*S+s matches d_out layout)
  gemm_bt<<<dim3(MM / 128, VV / 128), 256, 0, stream>>>(hs16, wout16, out, nullptr, MM, VV, HH);
}

// Round 2
// 1512.862 us; speedup vs baseline: 1.7522x; 1.0758x over previous
//
#include <hip/hip_runtime.h>

typedef unsigned short ushort_t;
typedef unsigned int uint_t;
typedef __attribute__((ext_vector_type(4))) float f32x4;
typedef __attribute__((ext_vector_type(8))) __bf16 bf16x8;

constexpr int BB = 32, SS = 128, EE = 512, HH = 512, VV = 32000;
constexpr int MM = BB * SS;   // 4096
constexpr int G3 = 3 * HH;    // 1536
constexpr int SCAN_WG = 32;   // 32 WGs, each owns 16 hidden cols (48 W_hh rows in LDS)

__device__ inline ushort_t f2b(float f) {
  union { float f; uint_t u; } v; v.f = f;
  uint_t r = v.u + 0x7fffu + ((v.u >> 16) & 1u);
  return (ushort_t)(r >> 16);
}
__device__ inline float b2f(ushort_t u) {
  union { float f; uint_t u; } v; v.u = ((uint_t)u) << 16;
  return v.f;
}

// ---------------- f32 -> bf16 converters ----------------
__global__ void cvt_bf16(const float* __restrict__ s, ushort_t* __restrict__ d, int n4) {
  int i = blockIdx.x * blockDim.x + threadIdx.x;
  if (i >= n4) return;
  float4 v = reinterpret_cast<const float4*>(s)[i];
  ushort4 o;
  o.x = f2b(v.x); o.y = f2b(v.y); o.z = f2b(v.z); o.w = f2b(v.w);
  reinterpret_cast<ushort4*>(d)[i] = o;
}

__global__ void cvt_split(const float* __restrict__ s, ushort_t* __restrict__ hi,
                          ushort_t* __restrict__ lo, int n4) {
  int i = blockIdx.x * blockDim.x + threadIdx.x;
  if (i >= n4) return;
  float4 v = reinterpret_cast<const float4*>(s)[i];
  float a[4] = {v.x, v.y, v.z, v.w};
  ushort4 oh, ol;
  ushort_t h;
  h = f2b(a[0]); oh.x = h; ol.x = f2b(a[0] - b2f(h));
  h = f2b(a[1]); oh.y = h; ol.y = f2b(a[1] - b2f(h));
  h = f2b(a[2]); oh.z = h; ol.z = f2b(a[2] - b2f(h));
  h = f2b(a[3]); oh.w = h; ol.w = f2b(a[3] - b2f(h));
  reinterpret_cast<ushort4*>(hi)[i] = oh;
  reinterpret_cast<ushort4*>(lo)[i] = ol;
}

// ---------------- bf16 B^T GEMM: C[M,N] = A[M,K] * B[N,K]^T (+bias[n]) ----------------
// 128x128 tile, 256 threads (4 waves, 2x2 wave grid of 64x64), BK=32,
// global_load_lds width-16 staging (m97 structure). Unchanged.
__global__ __launch_bounds__(256) void gemm_bt(
    const ushort_t* __restrict__ A, const ushort_t* __restrict__ B,
    float* __restrict__ C, const float* __restrict__ bias,
    int M, int N, int K) {
  __shared__ alignas(16) ushort_t As[128 * 32];
  __shared__ alignas(16) ushort_t Bs[128 * 32];
  const int tid = threadIdx.x;
  const int wave = tid >> 6, lane = tid & 63;
  const int l16 = lane & 15, quad = lane >> 4;
  const int m0 = blockIdx.x * 128, n0 = blockIdx.y * 128;
  const int wm = (wave & 1) * 64, wn = (wave >> 1) * 64;

  f32x4 acc[4][4] = {};
  const int cbase = wave * 64 + lane;  // chunk id, pass 0

  for (int kt = 0; kt < K; kt += 32) {
#pragma unroll
    for (int pass = 0; pass < 2; ++pass) {
      int c = cbase + pass * 256;     // 16B chunk index in tile [0,512)
      int r = c >> 2;                 // tile row
      int kc = (c & 3) * 8;           // bf16 elems into the 32-wide k slab
      const ushort_t* ga = A + (size_t)(m0 + r) * K + kt + kc;
      const ushort_t* gb = B + (size_t)(n0 + r) * K + kt + kc;
      int ldsoff = (wave * 64 + pass * 256) * 16;  // bytes, wave-uniform
      __builtin_amdgcn_global_load_lds(
          (const __attribute__((address_space(1))) void*)ga,
          (__attribute__((address_space(3))) void*)((char*)As + ldsoff), 16, 0, 0);
      __builtin_amdgcn_global_load_lds(
          (const __attribute__((address_space(1))) void*)gb,
          (__attribute__((address_space(3))) void*)((char*)Bs + ldsoff), 16, 0, 0);
    }
    __syncthreads();
    bf16x8 af[4], bf[4];
#pragma unroll
    for (int i = 0; i < 4; ++i)
      af[i] = *(const bf16x8*)&As[(wm + i * 16 + l16) * 32 + quad * 8];
#pragma unroll
    for (int j = 0; j < 4; ++j)
      bf[j] = *(const bf16x8*)&Bs[(wn + j * 16 + l16) * 32 + quad * 8];
#pragma unroll
    for (int i = 0; i < 4; ++i)
#pragma unroll
      for (int j = 0; j < 4; ++j)
        acc[i][j] = __builtin_amdgcn_mfma_f32_16x16x32_bf16(af[i], bf[j], acc[i][j], 0, 0, 0);
    __syncthreads();
  }
  // epilogue: D row = quad*4+reg, col = lane&15 (m89-verified layout)
#pragma unroll
  for (int i = 0; i < 4; ++i) {
    int row = m0 + wm + i * 16 + quad * 4;
#pragma unroll
    for (int j = 0; j < 4; ++j) {
      int col = n0 + wn + j * 16 + l16;
      float bv = bias ? bias[col] : 0.0f;
#pragma unroll
      for (int r = 0; r < 4; ++r)
        C[(size_t)(row + r) * N + col] = acc[i][j][r] + bv;
    }
  }
}

// ---------------- persistent GRU scan, v3 ----------------
// Same work decomposition as v2 (32 WGs x 16 cols, W_hh pinned in LDS,
// 4-wave K-split GEMM). Barrier redesigned for latency:
//  - NO __threadfence (no buffer_wbl2 / buffer_inv). Only hbhi/hblo cross WGs;
//    they are stored write-through via __hip_atomic_store(RELAXED, AGENT)
//    (vmcnt-acked at the coherence point; __syncthreads' vmcnt(0) drain is the
//    release) and read via __hip_atomic_load(RELAXED, AGENT) (cache-bypass,
//    so no L2 invalidate needed). hs stays lazily cached.
//  - hf32 eliminated: gate-phase thread (gb,gj) consumes exactly the h it
//    produced last step -> f32 h carried in registers. Bit-identical numerics.
//  - 4 per-K-quarter arrive counters (64B apart). Wave w polls only quarter w
//    (its GEMM A-operand K-range [w*128,(w+1)*128) = cols of WGs 8w..8w+7), so
//    each wave starts as soon as its 8 producers arrive. Every WG still needs
//    all 4 quarters per step across its 4 waves -> nobody runs >1 step ahead,
//    so the 2-deep ring stays race-free.
// Race tripwire: absmax must stay exactly 0.015625 (numerics unchanged);
// a shift suggests the relaxed barrier leaked -> revert to threadfence pair.
__global__ __launch_bounds__(256) void gru_scan(
    const float* __restrict__ xg,        // [4096,1536], row m=b*S+s
    const float* __restrict__ h0,        // [32,512]
    const float* __restrict__ b_hh,      // [1536]
    const ushort_t* __restrict__ whh_hi, // [1536,512]
    const ushort_t* __restrict__ whh_lo,
    ushort_t* __restrict__ hbhi,         // ring [2][32*512] (coherent)
    ushort_t* __restrict__ hblo,
    ushort_t* __restrict__ hs,           // [4096,512] bf16, row m=b*S+t (cached)
    int* __restrict__ bar) {             // 4 counters at bar[q*16]
  const int g = blockIdx.x;
  const int tid = threadIdx.x;
  const int wave = tid >> 6, lane = tid & 63;
  const int l16 = lane & 15, quad = lane >> 4;

  // 48 KB + 48 KB + 25.5 KB = 121.5 KB LDS -> 1 WG/CU.
  __shared__ alignas(16) ushort_t lds_whh_hi[48 * 512];
  __shared__ alignas(16) ushort_t lds_whh_lo[48 * 512];
  __shared__ float lds_part[4][3][32][17];

  // ---- one-time: stage this WG's W_hh slice into LDS, XOR-swizzled ----
  for (int c = tid; c < 48 * 64; c += 256) {
    int lr = c >> 6;                 // 0..47
    int kc = c & 63;                 // 16B chunk within row
    int grow = (lr >> 4) * 512 + g * 16 + (lr & 15);
    const f32x4* srch = (const f32x4*)(whh_hi + (size_t)grow * 512 + kc * 8);
    const f32x4* srcl = (const f32x4*)(whh_lo + (size_t)grow * 512 + kc * 8);
    int db = lr * 1024 + ((kc * 16) ^ ((lr & 7) << 4));
    *(f32x4*)((char*)lds_whh_hi + db) = *srch;
    *(f32x4*)((char*)lds_whh_lo + db) = *srcl;
  }
  __syncthreads();

  // ---- gate-phase per-thread geometry: 2 (b, col) outputs ----
  const int gb = tid >> 3;          // batch 0..31
  const int jj = (tid & 7) * 2;     // local col 0,2,..,14
  const int gj = g * 16 + jj;       // global hidden col
  const float bh_r0 = b_hh[gj],        bh_r1 = b_hh[gj + 1];
  const float bh_z0 = b_hh[512 + gj],  bh_z1 = b_hh[512 + gj + 1];
  const float bh_n0 = b_hh[1024 + gj], bh_n1 = b_hh[1024 + gj + 1];
  const float* xgp0 = xg + (size_t)gb * SS * G3 + gj;
  // f32 hidden state carried in registers (was hf32 ring)
  float hv0 = h0[gb * HH + gj], hv1 = h0[gb * HH + gj + 1];

  int* const barq   = bar + wave * 16;       // quarter this wave CONSUMES
  int* const bar_pr = bar + (g >> 3) * 16;   // quarter this WG PRODUCES

  union U16B { unsigned long long q[2]; bf16x8 v; };

  for (int t = 0; t < SS; ++t) {
    const int p = t & 1;

    // xg loads for the gate phase: plain cached, issued early, hidden under GEMM
    const float* xgp = xgp0 + (size_t)t * G3;
    float2 fxr = *(const float2*)(xgp);
    float2 fxz = *(const float2*)(xgp + 512);
    float2 fxn = *(const float2*)(xgp + 1024);

    // ---- per-wave poll: wait for this wave's K-quarter producers ----
    if (lane == 0) {
      int target = t * 8;            // trivially true at t==0
      while (__hip_atomic_load(barq, __ATOMIC_RELAXED, __HIP_MEMORY_SCOPE_AGENT) < target)
        __builtin_amdgcn_s_sleep(1);
    }
    asm volatile("" ::: "memory");   // no compile-time hoist of h loads above poll

    // ---- coherent preload of all A-fragments (h hi/lo) for this wave ----
    const ushort_t* hhi = hbhi + p * (BB * HH);
    const ushort_t* hlo = hblo + p * (BB * HH);
    const int kbase = wave * 128;
    bf16x8 ah[2][4], al[2][4];       // [mt][kk], all indices compile-time
#pragma unroll
    for (int kk = 0; kk < 4; ++kk) {
      const int kw = kbase + kk * 32 + quad * 8;
#pragma unroll
      for (int mt = 0; mt < 2; ++mt) {
        const unsigned long long* ph =
            (const unsigned long long*)(hhi + (size_t)(mt * 16 + l16) * HH + kw);
        const unsigned long long* pl =
            (const unsigned long long*)(hlo + (size_t)(mt * 16 + l16) * HH + kw);
        U16B th, tl;
        th.q[0] = __hip_atomic_load(ph,     __ATOMIC_RELAXED, __HIP_MEMORY_SCOPE_AGENT);
        th.q[1] = __hip_atomic_load(ph + 1, __ATOMIC_RELAXED, __HIP_MEMORY_SCOPE_AGENT);
        tl.q[0] = __hip_atomic_load(pl,     __ATOMIC_RELAXED, __HIP_MEMORY_SCOPE_AGENT);
        tl.q[1] = __hip_atomic_load(pl + 1, __ATOMIC_RELAXED, __HIP_MEMORY_SCOPE_AGENT);
        ah[mt][kk] = th.v;
        al[mt][kk] = tl.v;
      }
    }

    // ---- GEMM: hg[32,48] partial over this wave's K-quarter ----
    {
      f32x4 acc[2][3] = {};
#pragma unroll
      for (int kk = 0; kk < 4; ++kk) {
        const int kw = kbase + kk * 32 + quad * 8;
        bf16x8 bh[3], bl[3];
#pragma unroll
        for (int nt = 0; nt < 3; ++nt) {
          int lr = nt * 16 + l16;
          int db = lr * 1024 + ((kw * 2) ^ ((lr & 7) << 4));
          bh[nt] = *(const bf16x8*)((const char*)lds_whh_hi + db);
          bl[nt] = *(const bf16x8*)((const char*)lds_whh_lo + db);
        }
#pragma unroll
        for (int mt = 0; mt < 2; ++mt)
#pragma unroll
          for (int nt = 0; nt < 3; ++nt) {
            acc[mt][nt] = __builtin_amdgcn_mfma_f32_16x16x32_bf16(ah[mt][kk], bh[nt], acc[mt][nt], 0, 0, 0);
            acc[mt][nt] = __builtin_amdgcn_mfma_f32_16x16x32_bf16(ah[mt][kk], bl[nt], acc[mt][nt], 0, 0, 0);
            acc[mt][nt] = __builtin_amdgcn_mfma_f32_16x16x32_bf16(al[mt][kk], bh[nt], acc[mt][nt], 0, 0, 0);
          }
      }
      // partials -> LDS (C layout: row = quad*4+r, col = l16)
#pragma unroll
      for (int mt = 0; mt < 2; ++mt)
#pragma unroll
        for (int nt = 0; nt < 3; ++nt)
#pragma unroll
          for (int r = 0; r < 4; ++r)
            lds_part[wave][nt][mt * 16 + quad * 4 + r][l16] = acc[mt][nt][r];
    }
    __syncthreads();

    // ---- gate phase: reduce 4 K-partials, apply GRU nonlinearity ----
    {
      float xra[2] = {fxr.x, fxr.y};
      float xza[2] = {fxz.x, fxz.y};
      float xna[2] = {fxn.x, fxn.y};
      float hva[2] = {hv0, hv1};
      float bra[2] = {bh_r0, bh_r1};
      float bza[2] = {bh_z0, bh_z1};
      float bna[2] = {bh_n0, bh_n1};
      float outv[2]; ushort_t ohi[2], olo[2];
#pragma unroll
      for (int c = 0; c < 2; ++c) {
        int col = jj + c;
        float hr = lds_part[0][0][gb][col] + lds_part[1][0][gb][col]
                 + lds_part[2][0][gb][col] + lds_part[3][0][gb][col] + bra[c];
        float hz = lds_part[0][1][gb][col] + lds_part[1][1][gb][col]
                 + lds_part[2][1][gb][col] + lds_part[3][1][gb][col] + bza[c];
        float hn = lds_part[0][2][gb][col] + lds_part[1][2][gb][col]
                 + lds_part[2][2][gb][col] + lds_part[3][2][gb][col] + bna[c];
        float r = 1.f / (1.f + __expf(-(xra[c] + hr)));
        float z = 1.f / (1.f + __expf(-(xza[c] + hz)));
        float pre = xna[c] + r * hn;
        pre = fminf(fmaxf(pre, -15.f), 15.f);
        float e = __expf(2.f * pre);
        float n = (e - 1.f) / (e + 1.f);
        float hnew = (1.f - z) * n + z * hva[c];
        outv[c] = hnew;
        ushort_t hb = f2b(hnew);
        ohi[c] = hb;
        olo[c] = f2b(hnew - b2f(hb));
      }
      hv0 = outv[0]; hv1 = outv[1];  // register carry of f32 h
      ushort_t* hhi_n = hbhi + (p ^ 1) * (BB * HH);
      ushort_t* hlo_n = hblo + (p ^ 1) * (BB * HH);
      uint_t uh = (uint_t)ohi[0] | ((uint_t)ohi[1] << 16);
      uint_t ul = (uint_t)olo[0] | ((uint_t)olo[1] << 16);
      // write-through coherent ring stores (the only cross-WG data)
      __hip_atomic_store((uint_t*)(hhi_n + gb * HH + gj), uh,
                         __ATOMIC_RELAXED, __HIP_MEMORY_SCOPE_AGENT);
      __hip_atomic_store((uint_t*)(hlo_n + gb * HH + gj), ul,
                         __ATOMIC_RELAXED, __HIP_MEMORY_SCOPE_AGENT);
      // hs: kernel-lifetime only, stays cached
      ushort2 uh2; uh2.x = ohi[0]; uh2.y = ohi[1];
      *(ushort2*)(hs + (size_t)(gb * SS + t) * HH + gj) = uh2;
    }

    // ---- arrive: __syncthreads drains every thread's vmcnt (= release for
    // the write-through stores), then one relaxed RMW on this WG's quarter.
    __syncthreads();
    if (tid == 0)
      __hip_atomic_fetch_add(bar_pr, 1, __ATOMIC_RELAXED, __HIP_MEMORY_SCOPE_AGENT);
  }
}

extern "C" void kernel_launch(void* const* d_in, const int* in_sizes, int n_in,
                              void* d_out, int out_size, void* d_ws, size_t ws_size,
                              hipStream_t stream) {
  (void)in_sizes; (void)n_in; (void)out_size; (void)ws_size;
  const float* embed  = (const float*)d_in[0];  // [B,S,E]
  const float* hidden = (const float*)d_in[1];  // [1,B,H]
  const float* w_ih   = (const float*)d_in[2];  // [3H,E]
  const float* w_hh   = (const float*)d_in[3];  // [3H,H]
  const float* b_ih   = (const float*)d_in[4];  // [3H]
  const float* b_hh   = (const float*)d_in[5];  // [3H]
  const float* w_out  = (const float*)d_in[6];  // [V,H]
  float* out = (float*)d_out;

  char* ws = (char*)d_ws;
  size_t off = 0;
  auto alloc = [&](size_t bytes) {
    void* p = ws + off;
    off += (bytes + 255) & ~(size_t)255;
    return p;
  };
  float*    xg     = (float*)   alloc((size_t)MM * G3 * 4);   // 25.2 MB
  ushort_t* emb16  = (ushort_t*)alloc((size_t)MM * EE * 2);   // 4.2 MB
  ushort_t* wih16  = (ushort_t*)alloc((size_t)G3 * EE * 2);   // 1.5 MB
  ushort_t* whh_hi = (ushort_t*)alloc((size_t)G3 * HH * 2);   // 1.5 MB
  ushort_t* whh_lo = (ushort_t*)alloc((size_t)G3 * HH * 2);   // 1.5 MB
  ushort_t* wout16 = (ushort_t*)alloc((size_t)VV * HH * 2);   // 32.8 MB
  ushort_t* hs16   = (ushort_t*)alloc((size_t)MM * HH * 2);   // 4.2 MB
  ushort_t* hbhi   = (ushort_t*)alloc((size_t)2 * BB * HH * 2);
  ushort_t* hblo   = (ushort_t*)alloc((size_t)2 * BB * HH * 2);
  int*      bar    = (int*)     alloc(256);                   // 4 counters @ 64B

  hipMemsetAsync(bar, 0, 256, stream);

  cvt_bf16 <<<2048,  256, 0, stream>>>(embed, emb16, MM * EE / 4);
  cvt_bf16 <<<768,   256, 0, stream>>>(w_ih, wih16, G3 * EE / 4);
  cvt_split<<<768,   256, 0, stream>>>(w_hh, whh_hi, whh_lo, G3 * HH / 4);
  cvt_bf16 <<<16000, 256, 0, stream>>>(w_out, wout16, VV * HH / 4);
  cvt_split<<<16,    256, 0, stream>>>(hidden, hbhi, hblo, BB * HH / 4);

  // x-gates: xg[m, g] = embed[m,:] . w_ih[g,:] + b_ih[g]
  gemm_bt<<<dim3(MM / 128, G3 / 128), 256, 0, stream>>>(emb16, wih16, xg, b_ih, MM, G3, EE);

  gru_scan<<<SCAN_WG, 256, 0, stream>>>(xg, hidden, b_hh, whh_hi, whh_lo,
                                        hbhi, hblo, hs16, bar);

  // projection: out[m, v] = hs[m,:] . w_out[v,:]  (m = b*S+s matches d_out layout)
  gemm_bt<<<dim3(MM / 128, VV / 128), 256, 0, stream>>>(hs16, wout16, out, nullptr, MM, VV, HH);
}